// Round 7
// baseline (206.325 us; speedup 1.0000x reference)
//
#include <hip/hip_runtime.h>

typedef __attribute__((ext_vector_type(4))) float f32x4;
typedef __attribute__((ext_vector_type(8))) __bf16 bf16x8;
typedef __attribute__((ext_vector_type(4))) __bf16 bf16x4;

#define LOG_2PI 1.8378770664093453f

__device__ __forceinline__ float softplus_f(float x) {
  return fmaxf(x, 0.f) + log1pf(expf(-fabsf(x)));
}

// LDS-only barrier (decoder): waits LDS ops, leaves global loads in flight.
__device__ __forceinline__ void barrier_lds_only() {
  asm volatile("s_waitcnt lgkmcnt(0)\n\ts_barrier" ::: "memory");
}

// async global->LDS, 16B per lane; dest = wave-uniform base + lane*16
__device__ __forceinline__ void gload16(const void* g, void* l) {
  __builtin_amdgcn_global_load_lds(
      (const __attribute__((address_space(1))) void*)g,
      (__attribute__((address_space(3))) void*)l, 16, 0, 0);
}

// ---------------- prep: marks_proj (blocks 0..1023) + zero accs (block 1024)
__global__ void prep_kernel(const float* __restrict__ em,
                            const float* __restrict__ Wp,
                            const float* __restrict__ bp,
                            float* __restrict__ mp,
                            float* __restrict__ accs) {
  const int b = blockIdx.x;
  if (b == 1024) {
    if (threadIdx.x < 8) accs[threadIdx.x] = 0.f;
    return;
  }
  const int d = threadIdx.x;
  float s = bp[d];
  const float* emr = em + b * 128;
#pragma unroll 4
  for (int k = 0; k < 128; ++k) s += emr[k] * Wp[k * 128 + d];
  mp[b * 128 + d] = s;
}

// ---------------- fused intensity (traj blocks 0..1023, events 1024..1151) --
// Swapped MFMA: D[m=hidden][n=row]. z staged f32 via global_load_lds into a
// ring of 3 LDS buffers (fire-and-forget; issue t+2 at body t; counted
// s_waitcnt vmcnt(2) per barrier — never drained mid-loop). LDS XOR-swizzle
// via pre-swizzled per-lane GLOBAL source (linear LDS dest) + swizzled reads.
__global__ __launch_bounds__(512, 4) void intensity6_kernel(
    const float* __restrict__ z_traj, const float* __restrict__ z_ev,
    const float* __restrict__ W1, const float* __restrict__ b1,
    const float* __restrict__ W2, const float* __restrict__ b2,
    const float* __restrict__ base_i, const float* __restrict__ times,
    float* __restrict__ accs) {
  __shared__ __align__(16) float zb[3][32 * 128];  // 48 KB, swizzled f32
  __shared__ float s_part[16][32][9];              // 18.4 KB
  __shared__ __align__(16) float b1L[512];
  __shared__ __align__(16) float w2L[512];
  __shared__ float red[8];

  const int tid = threadIdx.x;
  const int wid = tid >> 6, lid = tid & 63;
  const int g = lid >> 4, q = lid & 15;
  const int cb = wid * 64;

  const int b = blockIdx.x;
  const bool traj = (b < 1024);
  const float* z = traj ? z_traj : z_ev;
  const int tile0 = (traj ? b : (b - 1024)) * 16;

  b1L[tid] = b1[tid];
  w2L[tid] = W2[tid];

  // W1 A-frags: frag[cf][kf] elem j = W1[kf*32+g*8+j][cb+cf*16+q]
  bf16x8 bw[4][4];
#pragma unroll
  for (int cf = 0; cf < 4; ++cf) {
    const int col = cb + cf * 16 + q;
#pragma unroll
    for (int kf = 0; kf < 4; ++kf) {
      bf16x8 f;
#pragma unroll
      for (int j = 0; j < 8; ++j) f[j] = (__bf16)W1[(kf * 32 + g * 8 + j) * 512 + col];
      bw[cf][kf] = f;
    }
  }
  const float sbias = b2[0] + base_i[0];

  // staging geometry: linear LDS (lane*16), inverse-swizzled global source.
  // involution: phys = L ^ (((L>>9)&7)<<4)   (row = L>>9, 512B f32 rows)
  const int loff0 = wid * 2048 + lid * 16;
  const int loff1 = loff0 + 1024;
  const int swz0 = loff0 ^ (((loff0 >> 9) & 7) << 4);
  const int swz1 = loff1 ^ (((loff1 >> 9) & 7) << 4);
  const int dst0 = wid * 2048;         // wave-uniform
  const int dst1 = wid * 2048 + 1024;  // wave-uniform

#define STAGE(TT, SB)                                                      \
  do {                                                                     \
    const char* gs = (const char*)(z + (size_t)(tile0 + (TT)) * 4096);     \
    char* lb = (char*)&zb[SB][0];                                          \
    gload16(gs + swz0, lb + dst0);                                         \
    gload16(gs + swz1, lb + dst1);                                         \
  } while (0)

  float kls = 0.f;

  // COMPUTE(T, CUR): swizzled f32 frag reads -> cvt bf16 -> 32 MFMA (rf-seq,
  // 16-reg acc) -> per-row partial -> s_part[T]. No barrier inside.
#define COMPUTE(T, CUR)                                                            \
  do {                                                                             \
    const char* zc = (const char*)&zb[CUR][0];                                     \
    _Pragma("unroll") for (int rf = 0; rf < 2; ++rf) {                             \
      const int row = rf * 16 + q;                                                 \
      const int rowb = row * 512;                                                  \
      const int sw = (row & 7) << 4;                                               \
      f32x4 acc[4] = {};                                                           \
      _Pragma("unroll") for (int kf = 0; kf < 4; ++kf) {                           \
        const int x0 = kf * 128 + g * 32;                                          \
        f32x4 a0 = *(const f32x4*)(zc + rowb + (x0 ^ sw));                         \
        f32x4 a1 = *(const f32x4*)(zc + rowb + ((x0 + 16) ^ sw));                  \
        if (traj) {                                                                \
          kls += a0[0] * a0[0] + a0[1] * a0[1] + a0[2] * a0[2] + a0[3] * a0[3];    \
          kls += a1[0] * a1[0] + a1[1] * a1[1] + a1[2] * a1[2] + a1[3] * a1[3];    \
        }                                                                          \
        bf16x8 af;                                                                 \
        _Pragma("unroll") for (int j = 0; j < 4; ++j) {                            \
          af[j] = (__bf16)a0[j];                                                   \
          af[4 + j] = (__bf16)a1[j];                                               \
        }                                                                          \
        _Pragma("unroll") for (int cf = 0; cf < 4; ++cf)                           \
          acc[cf] = __builtin_amdgcn_mfma_f32_16x16x32_bf16(bw[cf][kf], af, acc[cf], 0, 0, 0); \
      }                                                                            \
      float partial = 0.f;                                                         \
      _Pragma("unroll") for (int cf = 0; cf < 4; ++cf) {                           \
        const int c0 = cb + cf * 16 + g * 4;                                       \
        f32x4 bb = *(const f32x4*)&b1L[c0];                                        \
        f32x4 ww = *(const f32x4*)&w2L[c0];                                        \
        _Pragma("unroll") for (int i = 0; i < 4; ++i)                              \
          partial += fmaxf(acc[cf][i] + bb[i], 0.f) * ww[i];                       \
      }                                                                            \
      partial += __shfl_xor(partial, 16);                                          \
      partial += __shfl_xor(partial, 32);                                          \
      if (lid < 16) s_part[T][rf * 16 + lid][wid] = partial;                       \
    }                                                                              \
  } while (0)

  // prologue: stage tiles 0,1; wait tile0 (allow tile1 in flight); barrier
  STAGE(0, 0);
  STAGE(1, 1);
  asm volatile("s_waitcnt vmcnt(2) lgkmcnt(0)\n\ts_barrier" ::: "memory");

  int cur = 0;
#pragma unroll 1
  for (int t = 0; t < 14; ++t) {
    int sb = cur + 2;
    if (sb >= 3) sb -= 3;
    STAGE(t + 2, sb);  // fire-and-forget, 2 loads
    COMPUTE(t, cur);
    // wait tile t+1 (oldest pair), keep t+2's pair in flight; LDS drained
    asm volatile("s_waitcnt vmcnt(2) lgkmcnt(0)\n\ts_barrier" ::: "memory");
    ++cur;
    if (cur >= 3) cur -= 3;
  }
  COMPUTE(14, cur);
  asm volatile("s_waitcnt vmcnt(0) lgkmcnt(0)\n\ts_barrier" ::: "memory");
  ++cur;
  if (cur >= 3) cur -= 3;
  COMPUTE(15, cur);
  __syncthreads();
#undef COMPUTE
#undef STAGE

  // ---- batched finalize: 512 threads, one (tile,row) each ----
  float local;
  {
    const int tt = tid >> 5, r = tid & 31;
    float s = sbias;
#pragma unroll
    for (int w = 0; w < 8; ++w) s += s_part[tt][r][w];
    const float lam = softplus_f(s);
    if (traj) {
      const int R = (tile0 + tt) * 32 + r;
      const int ts = R >> 6;
      local = lam * (times[ts + 1] - times[ts]) * (1.f / 64.f);
    } else {
      local = logf(lam + 1e-8f) * (1.f / 64.f);
    }
  }
#pragma unroll
  for (int m = 32; m >= 1; m >>= 1) local += __shfl_xor(local, m);
  if (lid == 0) red[wid] = local;
  __syncthreads();
  if (tid == 0) {
    float s = 0.f;
#pragma unroll
    for (int w = 0; w < 8; ++w) s += red[w];
    atomicAdd(traj ? &accs[0] : &accs[1], s);
  }
  if (traj) {
    __syncthreads();
#pragma unroll
    for (int m = 32; m >= 1; m >>= 1) kls += __shfl_xor(kls, m);
    if (lid == 0) red[wid] = kls;
    __syncthreads();
    if (tid == 0) {
      float s = 0.f;
#pragma unroll
      for (int w = 0; w < 8; ++w) s += red[w];
      atomicAdd(&accs[3], s * 0.125f);  // each z element counted once per wave
    }
  }
}

// ---------------- decoder: swapped GEMM1 -> h (LDS) -> swapped GEMM2 -> logp
__global__ __launch_bounds__(512, 2) void decoder2_kernel(
    const float* __restrict__ z,
    const float* __restrict__ Wd1, const float* __restrict__ bd1,
    const float* __restrict__ Wd2, const float* __restrict__ bd2,
    const float* __restrict__ mp, float* __restrict__ recon_acc) {
  __shared__ __align__(16) __bf16 zbuf[2][32 * 128];  // 16 KB
  __shared__ __align__(16) __bf16 hbuf[32 * 512];     // 32 KB
  __shared__ float s_part[32][9];
  __shared__ float red[8];

  const int tid = threadIdx.x;
  const int wid = tid >> 6, lid = tid & 63;
  const int g = lid >> 4, q = lid & 15;
  const int cb = wid * 64;
  const int tile0 = blockIdx.x * 8;

  bf16x8 bw1[4][4];
  f32x4 bd1v[4];
#pragma unroll
  for (int cf = 0; cf < 4; ++cf) {
    const int col = cb + cf * 16 + q;
#pragma unroll
    for (int i = 0; i < 4; ++i) bd1v[cf][i] = bd1[cb + cf * 16 + g * 4 + i];
#pragma unroll
    for (int kf = 0; kf < 4; ++kf) {
      bf16x8 f;
#pragma unroll
      for (int j = 0; j < 8; ++j) f[j] = (__bf16)Wd1[(kf * 32 + g * 8 + j) * 512 + col];
      bw1[cf][kf] = f;
    }
  }
  const int dimf = wid * 16 + q;
  bf16x8 bw2[16];
#pragma unroll
  for (int kf2 = 0; kf2 < 16; ++kf2) {
    bf16x8 f;
#pragma unroll
    for (int j = 0; j < 8; ++j) f[j] = (__bf16)Wd2[(kf2 * 32 + g * 8 + j) * 128 + dimf];
    bw2[kf2] = f;
  }
  f32x4 bd2v;
#pragma unroll
  for (int i = 0; i < 4; ++i) bd2v[i] = bd2[wid * 16 + g * 4 + i];

  const int srow = tid >> 4, sk8 = (tid & 15) * 8;
  const int stg_byte = ((srow * 256 + sk8 * 2) ^ ((srow & 7) << 4));
  char* hb = (char*)hbuf;

  float local = 0.f;

  {
    const float* p = z + (size_t)tile0 * 4096 + tid * 8;
    f32x4 r0 = *(const f32x4*)p, r1 = *(const f32x4*)(p + 4);
    bf16x8 v;
#pragma unroll
    for (int j = 0; j < 4; ++j) { v[j] = (__bf16)r0[j]; v[4 + j] = (__bf16)r1[j]; }
    *(bf16x8*)((char*)zbuf[0] + stg_byte) = v;
  }
  f32x4 rA0, rA1, rB0, rB1;
  { const float* p = z + (size_t)(tile0 + 1) * 4096 + tid * 8; rA0 = *(const f32x4*)p; rA1 = *(const f32x4*)(p + 4); }
  { const float* p = z + (size_t)(tile0 + 2) * 4096 + tid * 8; rB0 = *(const f32x4*)p; rB1 = *(const f32x4*)(p + 4); }
  barrier_lds_only();

#define DBODY(T, ZC, RR0, RR1)                                                     \
  do {                                                                             \
    f32x4 acc1[2][4] = {};                                                         \
    char* zc = (char*)zbuf[ZC];                                                    \
    _Pragma("unroll") for (int kf = 0; kf < 4; ++kf) {                             \
      _Pragma("unroll") for (int rf = 0; rf < 2; ++rf) {                           \
        const int row = rf * 16 + q;                                               \
        bf16x8 a = *(const bf16x8*)(zc + ((row * 256 + kf * 64 + g * 16) ^ ((row & 7) << 4))); \
        _Pragma("unroll") for (int cf = 0; cf < 4; ++cf)                           \
          acc1[rf][cf] = __builtin_amdgcn_mfma_f32_16x16x32_bf16(bw1[cf][kf], a, acc1[rf][cf], 0, 0, 0); \
      }                                                                            \
    }                                                                              \
    {                                                                              \
      bf16x8 v;                                                                    \
      _Pragma("unroll") for (int j = 0; j < 4; ++j) { v[j] = (__bf16)RR0[j]; v[4 + j] = (__bf16)RR1[j]; } \
      *(bf16x8*)((char*)zbuf[(ZC) ^ 1] + stg_byte) = v;                            \
    }                                                                              \
    {                                                                              \
      int tl = (T) + 3; if (tl > 7) tl = 7;                                        \
      const float* p = z + (size_t)(tile0 + tl) * 4096 + tid * 8;                  \
      RR0 = *(const f32x4*)p; RR1 = *(const f32x4*)(p + 4);                        \
    }                                                                              \
    _Pragma("unroll") for (int rf = 0; rf < 2; ++rf) {                             \
      const int row = rf * 16 + q;                                                 \
      _Pragma("unroll") for (int cf = 0; cf < 4; ++cf) {                           \
        bf16x4 hv;                                                                 \
        _Pragma("unroll") for (int i = 0; i < 4; ++i)                              \
          hv[i] = (__bf16)fmaxf(acc1[rf][cf][i] + bd1v[cf][i], 0.f);               \
        const int byt = ((row * 1024 + (cb + cf * 16 + g * 4) * 2) ^ ((row & 7) << 4)); \
        *(bf16x4*)(hb + byt) = hv;                                                 \
      }                                                                            \
    }                                                                              \
    barrier_lds_only();                                                            \
    f32x4 acc2[2] = {};                                                            \
    _Pragma("unroll") for (int kf2 = 0; kf2 < 16; ++kf2) {                         \
      _Pragma("unroll") for (int rf2 = 0; rf2 < 2; ++rf2) {                        \
        const int row = rf2 * 16 + q;                                              \
        bf16x8 a = *(const bf16x8*)(hb + ((row * 1024 + kf2 * 64 + g * 16) ^ ((row & 7) << 4))); \
        acc2[rf2] = __builtin_amdgcn_mfma_f32_16x16x32_bf16(bw2[kf2], a, acc2[rf2], 0, 0, 0); \
      }                                                                            \
    }                                                                              \
    const int e = (tile0 + (T)) >> 1;                                              \
    _Pragma("unroll") for (int rf2 = 0; rf2 < 2; ++rf2) {                          \
      float partial = 0.f;                                                         \
      _Pragma("unroll") for (int i = 0; i < 4; ++i) {                              \
        const float xv = mp[e * 128 + wid * 16 + g * 4 + i];                       \
        const float d = xv - (acc2[rf2][i] + bd2v[i]);                             \
        partial += d * d;                                                          \
      }                                                                            \
      partial += __shfl_xor(partial, 16);                                          \
      partial += __shfl_xor(partial, 32);                                          \
      if (lid < 16) s_part[rf2 * 16 + lid][wid] = partial;                         \
    }                                                                              \
    barrier_lds_only();                                                            \
    if (tid < 32) {                                                                \
      float t2 = 0.f;                                                              \
      _Pragma("unroll") for (int w = 0; w < 8; ++w) t2 += s_part[tid][w];          \
      local += (-0.5f * t2 - 0.5f * 128.f * LOG_2PI) * (1.f / 64.f);               \
    }                                                                              \
  } while (0)

#pragma unroll 1
  for (int t = 0; t < 8; t += 2) {
    DBODY(t, 0, rA0, rA1);
    DBODY(t + 1, 1, rB0, rB1);
  }
#undef DBODY

  if (wid == 0) {
#pragma unroll
    for (int m = 16; m >= 1; m >>= 1) local += __shfl_xor(local, m);
    if (lid == 0) atomicAdd(recon_acc, local);
  }
}

// ---------------- finalize --------------------------------------------------
__global__ void finalize_kernel(const float* __restrict__ accs, float* __restrict__ out) {
  // accs: [0]=integral, [1]=log_intensity_sum, [2]=recon, [3]=sum(z_traj^2)
  const float kl = 0.01f * (accs[3] / 67108864.f);  // 8192*64*128
  const float elbo = accs[1] - accs[0] + accs[2] - kl;
  out[0] = -elbo;
}

extern "C" void kernel_launch(void* const* d_in, const int* in_sizes, int n_in,
                              void* d_out, int out_size, void* d_ws, size_t ws_size,
                              hipStream_t stream) {
  const float* event_marks = (const float*)d_in[0];
  const float* z_events = (const float*)d_in[1];
  const float* z_traj = (const float*)d_in[2];
  const float* times = (const float*)d_in[3];
  const float* Wp = (const float*)d_in[4];
  const float* bp = (const float*)d_in[5];
  const float* W1 = (const float*)d_in[6];
  const float* b1 = (const float*)d_in[7];
  const float* W2 = (const float*)d_in[8];
  const float* b2 = (const float*)d_in[9];
  const float* base_i = (const float*)d_in[10];
  const float* Wd1 = (const float*)d_in[11];
  const float* bd1 = (const float*)d_in[12];
  const float* Wd2 = (const float*)d_in[13];
  const float* bd2 = (const float*)d_in[14];

  float* mp = (float*)d_ws;                              // 1024*128 f32
  float* accs = (float*)((char*)d_ws + 1024 * 128 * 4);  // accumulators

  prep_kernel<<<1025, 128, 0, stream>>>(event_marks, Wp, bp, mp, accs);
  intensity6_kernel<<<1152, 512, 0, stream>>>(z_traj, z_events, W1, b1, W2, b2,
                                              base_i, times, accs);
  decoder2_kernel<<<256, 512, 0, stream>>>(z_events, Wd1, bd1, Wd2, bd2, mp,
                                           &accs[2]);
  finalize_kernel<<<1, 1, 0, stream>>>(accs, (float*)d_out);
}

// Round 8
// 151.631 us; speedup vs baseline: 1.3607x; 1.3607x over previous
//
#include <hip/hip_runtime.h>

typedef __attribute__((ext_vector_type(4))) float f32x4;
typedef __attribute__((ext_vector_type(8))) __bf16 bf16x8;
typedef __attribute__((ext_vector_type(4))) __bf16 bf16x4;

#define LOG_2PI 1.8378770664093453f

__device__ __forceinline__ float softplus_f(float x) {
  return fmaxf(x, 0.f) + log1pf(expf(-fabsf(x)));
}

__device__ __forceinline__ void barrier_lds_only() {
  asm volatile("s_waitcnt lgkmcnt(0)\n\ts_barrier" ::: "memory");
}

// ---------------- prep: marks_proj (blocks 0..1023) + zero accs (block 1024)
__global__ void prep_kernel(const float* __restrict__ em,
                            const float* __restrict__ Wp,
                            const float* __restrict__ bp,
                            float* __restrict__ mp,
                            float* __restrict__ accs) {
  const int b = blockIdx.x;
  if (b == 1024) {
    if (threadIdx.x < 8) accs[threadIdx.x] = 0.f;
    return;
  }
  const int d = threadIdx.x;
  float s = bp[d];
  const float* emr = em + b * 128;
#pragma unroll 4
  for (int k = 0; k < 128; ++k) s += emr[k] * Wp[k * 128 + d];
  mp[b * 128 + d] = s;
}

// ---------------- intensity: waves own rows; W1 (bf16) in LDS ---------------
// 256 blocks x 8 waves = 2048 waves; wave gw owns tiles [gw*9, gw*9+9) of
// 18432 32-row tiles (0..16383 traj, 16384..18431 events). No in-loop
// barriers: z loads go straight to registers as MFMA B-frags (one tile
// lookahead, pinned by sched_barrier); hidden-dim loop reads swizzled W
// frags from LDS; per-row sum completes in-wave with 2 shuffles.
__global__ __launch_bounds__(512, 1) void intensity7_kernel(
    const float* __restrict__ z_traj, const float* __restrict__ z_ev,
    const float* __restrict__ W1, const float* __restrict__ b1,
    const float* __restrict__ W2, const float* __restrict__ b2,
    const float* __restrict__ base_i, const float* __restrict__ times,
    float* __restrict__ accs) {
  __shared__ __align__(16) __bf16 w1t[512 * 128];  // 128 KB: W1^T, swizzled
  __shared__ __align__(16) float b1L[512];
  __shared__ __align__(16) float w2L[512];
  __shared__ float red[8][4];

  const int tid = threadIdx.x;
  const int wid = tid >> 6, lid = tid & 63;
  const int g = lid >> 4, q = lid & 15;

  const int gw = blockIdx.x * 8 + wid;
  const int t0 = gw * 9;

  // ---- issue first tile's z loads immediately (fire early) ----
  f32x4 rz[2][4][2];
#define LOADT(TILE)                                                            \
  do {                                                                         \
    const float* zp = ((TILE) < 16384)                                         \
                          ? z_traj + (size_t)(TILE) * 4096                     \
                          : z_ev + (size_t)((TILE) - 16384) * 4096;            \
    _Pragma("unroll") for (int s = 0; s < 2; ++s) {                            \
      _Pragma("unroll") for (int kf = 0; kf < 4; ++kf) {                       \
        const float* pp = zp + (s * 16 + q) * 128 + kf * 32 + g * 8;           \
        rz[s][kf][0] = *(const f32x4*)pp;                                      \
        rz[s][kf][1] = *(const f32x4*)(pp + 4);                                \
      }                                                                        \
    }                                                                          \
  } while (0)
  LOADT(t0);

  // ---- one-time W1^T -> LDS (bf16, col-XOR swizzle), b1/W2 -> LDS ----
  // thread t owns column t: w1t byte = t*256 + k*2, swizzled ^((t&7)<<4).
  {
    const float* wcol = W1 + tid;  // W1[k][tid], row stride 512
    char* wb = (char*)w1t;
    const int colbase = tid * 256;
    const int sw = (tid & 7) << 4;
#pragma unroll 8
    for (int k = 0; k < 128; k += 2) {
      float a = wcol[(size_t)k * 512];
      float c = wcol[(size_t)(k + 1) * 512];
      union { __bf16 h[2]; unsigned u; } pk;
      pk.h[0] = (__bf16)a;
      pk.h[1] = (__bf16)c;
      *(unsigned*)(wb + (colbase + ((k * 2) ^ sw))) = pk.u;
    }
    b1L[tid] = b1[tid];
    w2L[tid] = W2[tid];
  }
  const float sbias = b2[0] + base_i[0];
  barrier_lds_only();  // W ready; z register loads stay in flight

  float integral_loc = 0.f, logsum_loc = 0.f, kls = 0.f;
  const char* wb = (const char*)w1t;
  const int wsw = (q & 7) << 4;

#pragma unroll 1
  for (int i = 0; i < 9; ++i) {
    const int tile = t0 + i;
    const bool traj_t = (tile < 16384);

    // cvt current tile raws -> B-frags (+ kls); then issue next tile's loads
    bf16x8 fr[2][4];
#pragma unroll
    for (int s = 0; s < 2; ++s) {
#pragma unroll
      for (int kf = 0; kf < 4; ++kf) {
        f32x4 a0 = rz[s][kf][0], a1 = rz[s][kf][1];
        if (traj_t) {
          kls += a0[0] * a0[0] + a0[1] * a0[1] + a0[2] * a0[2] + a0[3] * a0[3];
          kls += a1[0] * a1[0] + a1[1] * a1[1] + a1[2] * a1[2] + a1[3] * a1[3];
        }
        bf16x8 f;
#pragma unroll
        for (int j = 0; j < 4; ++j) {
          f[j] = (__bf16)a0[j];
          f[4 + j] = (__bf16)a1[j];
        }
        fr[s][kf] = f;
      }
    }
    if (i < 8) LOADT(tile + 1);
    __builtin_amdgcn_sched_barrier(0);  // pin load issue before hidden loop

    // hidden loop: 32 c-blocks; acc D[m=hidden][n=row]
    float rowacc0 = 0.f, rowacc1 = 0.f;
#pragma unroll 4
    for (int c = 0; c < 32; ++c) {
      f32x4 a0 = {}, a1 = {};
#pragma unroll
      for (int kf = 0; kf < 4; ++kf) {
        bf16x8 wf = *(const bf16x8*)(wb + c * 4096 + q * 256 +
                                     ((kf * 64 + g * 16) ^ wsw));
        a0 = __builtin_amdgcn_mfma_f32_16x16x32_bf16(wf, fr[0][kf], a0, 0, 0, 0);
        a1 = __builtin_amdgcn_mfma_f32_16x16x32_bf16(wf, fr[1][kf], a1, 0, 0, 0);
      }
      f32x4 bb = *(const f32x4*)&b1L[c * 16 + g * 4];
      f32x4 ww = *(const f32x4*)&w2L[c * 16 + g * 4];
#pragma unroll
      for (int ii = 0; ii < 4; ++ii) {
        rowacc0 += fmaxf(a0[ii] + bb[ii], 0.f) * ww[ii];
        rowacc1 += fmaxf(a1[ii] + bb[ii], 0.f) * ww[ii];
      }
    }
    // combine the 4 g-groups -> full 512-col row sums (indexed by q)
    rowacc0 += __shfl_xor(rowacc0, 16);
    rowacc0 += __shfl_xor(rowacc0, 32);
    rowacc1 += __shfl_xor(rowacc1, 16);
    rowacc1 += __shfl_xor(rowacc1, 32);

    // row finish: lanes 0..31 each own one row of the 32-row tile
    if (lid < 32) {
      const float rs = (lid < 16) ? rowacc0 : rowacc1;
      const float lam = softplus_f(rs + sbias);
      if (traj_t) {
        const int R = tile * 32 + lid;
        const int ts = R >> 6;
        integral_loc += lam * (times[ts + 1] - times[ts]) * (1.f / 64.f);
      } else {
        logsum_loc += logf(lam + 1e-8f) * (1.f / 64.f);
      }
    }
  }
#undef LOADT

  // ---- wave reduce 3 accumulators, block reduce, 3 atomics ----
#pragma unroll
  for (int m = 32; m >= 1; m >>= 1) {
    integral_loc += __shfl_xor(integral_loc, m);
    logsum_loc += __shfl_xor(logsum_loc, m);
    kls += __shfl_xor(kls, m);
  }
  if (lid == 0) {
    red[wid][0] = integral_loc;
    red[wid][1] = logsum_loc;
    red[wid][2] = kls;
  }
  __syncthreads();
  if (tid == 0) {
    float I = 0.f, L = 0.f, K = 0.f;
#pragma unroll
    for (int w = 0; w < 8; ++w) {
      I += red[w][0];
      L += red[w][1];
      K += red[w][2];
    }
    atomicAdd(&accs[0], I);
    atomicAdd(&accs[1], L);
    atomicAdd(&accs[3], K);
  }
}

// ---------------- decoder: swapped GEMM1 -> h (LDS) -> swapped GEMM2 -> logp
__global__ __launch_bounds__(512, 2) void decoder2_kernel(
    const float* __restrict__ z,
    const float* __restrict__ Wd1, const float* __restrict__ bd1,
    const float* __restrict__ Wd2, const float* __restrict__ bd2,
    const float* __restrict__ mp, float* __restrict__ recon_acc) {
  __shared__ __align__(16) __bf16 zbuf[2][32 * 128];  // 16 KB
  __shared__ __align__(16) __bf16 hbuf[32 * 512];     // 32 KB
  __shared__ float s_part[32][9];
  __shared__ float red[8];

  const int tid = threadIdx.x;
  const int wid = tid >> 6, lid = tid & 63;
  const int g = lid >> 4, q = lid & 15;
  const int cb = wid * 64;
  const int tile0 = blockIdx.x * 8;

  bf16x8 bw1[4][4];
  f32x4 bd1v[4];
#pragma unroll
  for (int cf = 0; cf < 4; ++cf) {
    const int col = cb + cf * 16 + q;
#pragma unroll
    for (int i = 0; i < 4; ++i) bd1v[cf][i] = bd1[cb + cf * 16 + g * 4 + i];
#pragma unroll
    for (int kf = 0; kf < 4; ++kf) {
      bf16x8 f;
#pragma unroll
      for (int j = 0; j < 8; ++j) f[j] = (__bf16)Wd1[(kf * 32 + g * 8 + j) * 512 + col];
      bw1[cf][kf] = f;
    }
  }
  const int dimf = wid * 16 + q;
  bf16x8 bw2[16];
#pragma unroll
  for (int kf2 = 0; kf2 < 16; ++kf2) {
    bf16x8 f;
#pragma unroll
    for (int j = 0; j < 8; ++j) f[j] = (__bf16)Wd2[(kf2 * 32 + g * 8 + j) * 128 + dimf];
    bw2[kf2] = f;
  }
  f32x4 bd2v;
#pragma unroll
  for (int i = 0; i < 4; ++i) bd2v[i] = bd2[wid * 16 + g * 4 + i];

  const int srow = tid >> 4, sk8 = (tid & 15) * 8;
  const int stg_byte = ((srow * 256 + sk8 * 2) ^ ((srow & 7) << 4));
  char* hb = (char*)hbuf;

  float local = 0.f;

  {
    const float* p = z + (size_t)tile0 * 4096 + tid * 8;
    f32x4 r0 = *(const f32x4*)p, r1 = *(const f32x4*)(p + 4);
    bf16x8 v;
#pragma unroll
    for (int j = 0; j < 4; ++j) { v[j] = (__bf16)r0[j]; v[4 + j] = (__bf16)r1[j]; }
    *(bf16x8*)((char*)zbuf[0] + stg_byte) = v;
  }
  f32x4 rA0, rA1, rB0, rB1;
  { const float* p = z + (size_t)(tile0 + 1) * 4096 + tid * 8; rA0 = *(const f32x4*)p; rA1 = *(const f32x4*)(p + 4); }
  { const float* p = z + (size_t)(tile0 + 2) * 4096 + tid * 8; rB0 = *(const f32x4*)p; rB1 = *(const f32x4*)(p + 4); }
  barrier_lds_only();

#define DBODY(T, ZC, RR0, RR1)                                                     \
  do {                                                                             \
    f32x4 acc1[2][4] = {};                                                         \
    char* zc = (char*)zbuf[ZC];                                                    \
    _Pragma("unroll") for (int kf = 0; kf < 4; ++kf) {                             \
      _Pragma("unroll") for (int rf = 0; rf < 2; ++rf) {                           \
        const int row = rf * 16 + q;                                               \
        bf16x8 a = *(const bf16x8*)(zc + ((row * 256 + kf * 64 + g * 16) ^ ((row & 7) << 4))); \
        _Pragma("unroll") for (int cf = 0; cf < 4; ++cf)                           \
          acc1[rf][cf] = __builtin_amdgcn_mfma_f32_16x16x32_bf16(bw1[cf][kf], a, acc1[rf][cf], 0, 0, 0); \
      }                                                                            \
    }                                                                              \
    {                                                                              \
      bf16x8 v;                                                                    \
      _Pragma("unroll") for (int j = 0; j < 4; ++j) { v[j] = (__bf16)RR0[j]; v[4 + j] = (__bf16)RR1[j]; } \
      *(bf16x8*)((char*)zbuf[(ZC) ^ 1] + stg_byte) = v;                            \
    }                                                                              \
    {                                                                              \
      int tl = (T) + 3; if (tl > 7) tl = 7;                                        \
      const float* p = z + (size_t)(tile0 + tl) * 4096 + tid * 8;                  \
      RR0 = *(const f32x4*)p; RR1 = *(const f32x4*)(p + 4);                        \
    }                                                                              \
    _Pragma("unroll") for (int rf = 0; rf < 2; ++rf) {                             \
      const int row = rf * 16 + q;                                                 \
      _Pragma("unroll") for (int cf = 0; cf < 4; ++cf) {                           \
        bf16x4 hv;                                                                 \
        _Pragma("unroll") for (int i = 0; i < 4; ++i)                              \
          hv[i] = (__bf16)fmaxf(acc1[rf][cf][i] + bd1v[cf][i], 0.f);               \
        const int byt = ((row * 1024 + (cb + cf * 16 + g * 4) * 2) ^ ((row & 7) << 4)); \
        *(bf16x4*)(hb + byt) = hv;                                                 \
      }                                                                            \
    }                                                                              \
    barrier_lds_only();                                                            \
    f32x4 acc2[2] = {};                                                            \
    _Pragma("unroll") for (int kf2 = 0; kf2 < 16; ++kf2) {                         \
      _Pragma("unroll") for (int rf2 = 0; rf2 < 2; ++rf2) {                        \
        const int row = rf2 * 16 + q;                                              \
        bf16x8 a = *(const bf16x8*)(hb + ((row * 1024 + kf2 * 64 + g * 16) ^ ((row & 7) << 4))); \
        acc2[rf2] = __builtin_amdgcn_mfma_f32_16x16x32_bf16(bw2[kf2], a, acc2[rf2], 0, 0, 0); \
      }                                                                            \
    }                                                                              \
    const int e = (tile0 + (T)) >> 1;                                              \
    _Pragma("unroll") for (int rf2 = 0; rf2 < 2; ++rf2) {                          \
      float partial = 0.f;                                                         \
      _Pragma("unroll") for (int i = 0; i < 4; ++i) {                              \
        const float xv = mp[e * 128 + wid * 16 + g * 4 + i];                       \
        const float d = xv - (acc2[rf2][i] + bd2v[i]);                             \
        partial += d * d;                                                          \
      }                                                                            \
      partial += __shfl_xor(partial, 16);                                          \
      partial += __shfl_xor(partial, 32);                                          \
      if (lid < 16) s_part[rf2 * 16 + lid][wid] = partial;                         \
    }                                                                              \
    barrier_lds_only();                                                            \
    if (tid < 32) {                                                                \
      float t2 = 0.f;                                                              \
      _Pragma("unroll") for (int w = 0; w < 8; ++w) t2 += s_part[tid][w];          \
      local += (-0.5f * t2 - 0.5f * 128.f * LOG_2PI) * (1.f / 64.f);               \
    }                                                                              \
  } while (0)

#pragma unroll 1
  for (int t = 0; t < 8; t += 2) {
    DBODY(t, 0, rA0, rA1);
    DBODY(t + 1, 1, rB0, rB1);
  }
#undef DBODY

  if (wid == 0) {
#pragma unroll
    for (int m = 16; m >= 1; m >>= 1) local += __shfl_xor(local, m);
    if (lid == 0) atomicAdd(recon_acc, local);
  }
}

// ---------------- finalize --------------------------------------------------
__global__ void finalize_kernel(const float* __restrict__ accs, float* __restrict__ out) {
  // accs: [0]=integral, [1]=log_intensity_sum, [2]=recon, [3]=sum(z_traj^2)
  const float kl = 0.01f * (accs[3] / 67108864.f);  // 8192*64*128
  const float elbo = accs[1] - accs[0] + accs[2] - kl;
  out[0] = -elbo;
}

extern "C" void kernel_launch(void* const* d_in, const int* in_sizes, int n_in,
                              void* d_out, int out_size, void* d_ws, size_t ws_size,
                              hipStream_t stream) {
  const float* event_marks = (const float*)d_in[0];
  const float* z_events = (const float*)d_in[1];
  const float* z_traj = (const float*)d_in[2];
  const float* times = (const float*)d_in[3];
  const float* Wp = (const float*)d_in[4];
  const float* bp = (const float*)d_in[5];
  const float* W1 = (const float*)d_in[6];
  const float* b1 = (const float*)d_in[7];
  const float* W2 = (const float*)d_in[8];
  const float* b2 = (const float*)d_in[9];
  const float* base_i = (const float*)d_in[10];
  const float* Wd1 = (const float*)d_in[11];
  const float* bd1 = (const float*)d_in[12];
  const float* Wd2 = (const float*)d_in[13];
  const float* bd2 = (const float*)d_in[14];

  float* mp = (float*)d_ws;                              // 1024*128 f32
  float* accs = (float*)((char*)d_ws + 1024 * 128 * 4);  // accumulators

  prep_kernel<<<1025, 128, 0, stream>>>(event_marks, Wp, bp, mp, accs);
  intensity7_kernel<<<256, 512, 0, stream>>>(z_traj, z_events, W1, b1, W2, b2,
                                             base_i, times, accs);
  decoder2_kernel<<<256, 512, 0, stream>>>(z_events, Wd1, bd1, Wd2, bd2, mp,
                                           &accs[2]);
  finalize_kernel<<<1, 1, 0, stream>>>(accs, (float*)d_out);
}

// Round 9
// 148.268 us; speedup vs baseline: 1.3916x; 1.0227x over previous
//
#include <hip/hip_runtime.h>

typedef __attribute__((ext_vector_type(4))) float f32x4;
typedef __attribute__((ext_vector_type(8))) __bf16 bf16x8;
typedef __attribute__((ext_vector_type(4))) __bf16 bf16x4;

#define LOG_2PI 1.8378770664093453f

__device__ __forceinline__ float softplus_f(float x) {
  return fmaxf(x, 0.f) + log1pf(expf(-fabsf(x)));
}

__device__ __forceinline__ void barrier_lds_only() {
  asm volatile("s_waitcnt lgkmcnt(0)\n\ts_barrier" ::: "memory");
}

// ---------------- prep: marks_proj (blocks 0..1023) + zero accs (block 1024)
__global__ void prep_kernel(const float* __restrict__ em,
                            const float* __restrict__ Wp,
                            const float* __restrict__ bp,
                            float* __restrict__ mp,
                            float* __restrict__ accs) {
  const int b = blockIdx.x;
  if (b == 1024) {
    if (threadIdx.x < 8) accs[threadIdx.x] = 0.f;
    return;
  }
  const int d = threadIdx.x;
  float s = bp[d];
  const float* emr = em + b * 128;
#pragma unroll 4
  for (int k = 0; k < 128; ++k) s += emr[k] * Wp[k * 128 + d];
  mp[b * 128 + d] = s;
}

// ---------------- intensity: waves own row-PAIRS; W1 (bf16) in LDS ----------
// 256 blocks x 12 waves = 3072 waves; wave gw owns pairs {gw, gw+3072,
// gw+6144} of 9216 64-row pairs (0..8191 traj == timestep p; 8192..9215
// events). No in-loop barriers. Per pair: 64 rows of z -> 16 B-frags in
// registers; hidden loop reads each swizzled W-frag ONCE and feeds 4 MFMA
// (64-row reuse halves LDS traffic vs 32-row tiles). Row sums finish in-wave.
__global__ __launch_bounds__(768, 3) void intensity8_kernel(
    const float* __restrict__ z_traj, const float* __restrict__ z_ev,
    const float* __restrict__ W1, const float* __restrict__ b1,
    const float* __restrict__ W2, const float* __restrict__ b2,
    const float* __restrict__ base_i, const float* __restrict__ times,
    float* __restrict__ accs) {
  __shared__ __align__(16) __bf16 w1t[512 * 128];  // 128 KB: W1^T, swizzled
  __shared__ __align__(16) float b1L[512];
  __shared__ __align__(16) float w2L[512];
  __shared__ float red[12][4];

  const int tid = threadIdx.x;
  const int wid = tid >> 6, lid = tid & 63;
  const int g = lid >> 4, q = lid & 15;

  // ---- one-time W1^T -> LDS (bf16, col-XOR swizzle), b1/W2 -> LDS ----
  // thread t (<512) owns column t: byte = t*256 + k*2, swizzled ^((t&7)<<4).
  if (tid < 512) {
    const float* wcol = W1 + tid;  // W1[k][tid], row stride 512
    char* wb = (char*)w1t;
    const int colbase = tid * 256;
    const int sw = (tid & 7) << 4;
#pragma unroll 8
    for (int k = 0; k < 128; k += 2) {
      float a = wcol[(size_t)k * 512];
      float c = wcol[(size_t)(k + 1) * 512];
      union { __bf16 h[2]; unsigned u; } pk;
      pk.h[0] = (__bf16)a;
      pk.h[1] = (__bf16)c;
      *(unsigned*)(wb + (colbase + ((k * 2) ^ sw))) = pk.u;
    }
    b1L[tid] = b1[tid];
    w2L[tid] = W2[tid];
  }
  const float sbias = b2[0] + base_i[0];
  barrier_lds_only();

  const int gw = blockIdx.x * 12 + wid;
  float integral_loc = 0.f, logsum_loc = 0.f, kls = 0.f;
  const char* wb = (const char*)w1t;
  const int wsw = (q & 7) << 4;

#pragma unroll 1
  for (int p = gw; p < 9216; p += 3072) {
    const bool traj_p = (p < 8192);
    const float* zbase = traj_p ? (z_traj + (size_t)p * 8192)
                                : (z_ev + (size_t)(p - 8192) * 8192);

    // ---- load 64 rows -> 16 B-frags (per s-group staging, + kls) ----
    bf16x8 fr[4][4];
#pragma unroll
    for (int s = 0; s < 4; ++s) {
      const float* rp = zbase + (s * 16 + q) * 128 + g * 8;
      f32x4 ld[4][2];
#pragma unroll
      for (int kf = 0; kf < 4; ++kf) {
        ld[kf][0] = *(const f32x4*)(rp + kf * 32);
        ld[kf][1] = *(const f32x4*)(rp + kf * 32 + 4);
      }
#pragma unroll
      for (int kf = 0; kf < 4; ++kf) {
        f32x4 a0 = ld[kf][0], a1 = ld[kf][1];
        if (traj_p) {
          kls += a0[0] * a0[0] + a0[1] * a0[1] + a0[2] * a0[2] + a0[3] * a0[3];
          kls += a1[0] * a1[0] + a1[1] * a1[1] + a1[2] * a1[2] + a1[3] * a1[3];
        }
        bf16x8 f;
#pragma unroll
        for (int j = 0; j < 4; ++j) {
          f[j] = (__bf16)a0[j];
          f[4 + j] = (__bf16)a1[j];
        }
        fr[s][kf] = f;
      }
    }

    // ---- hidden loop: 32 c-blocks; each W-frag read feeds 4 MFMA ----
    float rowacc0 = 0.f, rowacc1 = 0.f, rowacc2 = 0.f, rowacc3 = 0.f;
#pragma unroll 2
    for (int c = 0; c < 32; ++c) {
      f32x4 a0 = {}, a1 = {}, a2 = {}, a3 = {};
#pragma unroll
      for (int kf = 0; kf < 4; ++kf) {
        bf16x8 wf = *(const bf16x8*)(wb + c * 4096 + q * 256 +
                                     ((kf * 64 + g * 16) ^ wsw));
        a0 = __builtin_amdgcn_mfma_f32_16x16x32_bf16(wf, fr[0][kf], a0, 0, 0, 0);
        a1 = __builtin_amdgcn_mfma_f32_16x16x32_bf16(wf, fr[1][kf], a1, 0, 0, 0);
        a2 = __builtin_amdgcn_mfma_f32_16x16x32_bf16(wf, fr[2][kf], a2, 0, 0, 0);
        a3 = __builtin_amdgcn_mfma_f32_16x16x32_bf16(wf, fr[3][kf], a3, 0, 0, 0);
      }
      f32x4 bb = *(const f32x4*)&b1L[c * 16 + g * 4];
      f32x4 ww = *(const f32x4*)&w2L[c * 16 + g * 4];
#pragma unroll
      for (int ii = 0; ii < 4; ++ii) {
        rowacc0 += fmaxf(a0[ii] + bb[ii], 0.f) * ww[ii];
        rowacc1 += fmaxf(a1[ii] + bb[ii], 0.f) * ww[ii];
        rowacc2 += fmaxf(a2[ii] + bb[ii], 0.f) * ww[ii];
        rowacc3 += fmaxf(a3[ii] + bb[ii], 0.f) * ww[ii];
      }
    }
    // combine 4 g-groups -> full 512-col row sums (valid at every lane's q)
    rowacc0 += __shfl_xor(rowacc0, 16);
    rowacc0 += __shfl_xor(rowacc0, 32);
    rowacc1 += __shfl_xor(rowacc1, 16);
    rowacc1 += __shfl_xor(rowacc1, 32);
    rowacc2 += __shfl_xor(rowacc2, 16);
    rowacc2 += __shfl_xor(rowacc2, 32);
    rowacc3 += __shfl_xor(rowacc3, 16);
    rowacc3 += __shfl_xor(rowacc3, 32);

    // lane lid owns row (p*64 + lid): pick rowacc[lid>>4] at q = lid&15
    {
      const int s = lid >> 4;
      const float rs = (s == 0) ? rowacc0 : (s == 1) ? rowacc1
                     : (s == 2) ? rowacc2 : rowacc3;
      const float lam = softplus_f(rs + sbias);
      if (traj_p) {
        integral_loc += lam * (times[p + 1] - times[p]) * (1.f / 64.f);
      } else {
        logsum_loc += logf(lam + 1e-8f) * (1.f / 64.f);
      }
    }
  }

  // ---- wave reduce 3 accumulators, block reduce, 3 atomics ----
#pragma unroll
  for (int m = 32; m >= 1; m >>= 1) {
    integral_loc += __shfl_xor(integral_loc, m);
    logsum_loc += __shfl_xor(logsum_loc, m);
    kls += __shfl_xor(kls, m);
  }
  if (lid == 0) {
    red[wid][0] = integral_loc;
    red[wid][1] = logsum_loc;
    red[wid][2] = kls;
  }
  __syncthreads();
  if (tid == 0) {
    float I = 0.f, L = 0.f, K = 0.f;
#pragma unroll
    for (int w = 0; w < 12; ++w) {
      I += red[w][0];
      L += red[w][1];
      K += red[w][2];
    }
    atomicAdd(&accs[0], I);
    atomicAdd(&accs[1], L);
    atomicAdd(&accs[3], K);
  }
}

// ---------------- decoder: swapped GEMM1 -> h (LDS) -> swapped GEMM2 -> logp
__global__ __launch_bounds__(512, 2) void decoder2_kernel(
    const float* __restrict__ z,
    const float* __restrict__ Wd1, const float* __restrict__ bd1,
    const float* __restrict__ Wd2, const float* __restrict__ bd2,
    const float* __restrict__ mp, float* __restrict__ recon_acc) {
  __shared__ __align__(16) __bf16 zbuf[2][32 * 128];  // 16 KB
  __shared__ __align__(16) __bf16 hbuf[32 * 512];     // 32 KB
  __shared__ float s_part[32][9];
  __shared__ float red[8];

  const int tid = threadIdx.x;
  const int wid = tid >> 6, lid = tid & 63;
  const int g = lid >> 4, q = lid & 15;
  const int cb = wid * 64;
  const int tile0 = blockIdx.x * 4;

  bf16x8 bw1[4][4];
  f32x4 bd1v[4];
#pragma unroll
  for (int cf = 0; cf < 4; ++cf) {
    const int col = cb + cf * 16 + q;
#pragma unroll
    for (int i = 0; i < 4; ++i) bd1v[cf][i] = bd1[cb + cf * 16 + g * 4 + i];
#pragma unroll
    for (int kf = 0; kf < 4; ++kf) {
      bf16x8 f;
#pragma unroll
      for (int j = 0; j < 8; ++j) f[j] = (__bf16)Wd1[(kf * 32 + g * 8 + j) * 512 + col];
      bw1[cf][kf] = f;
    }
  }
  const int dimf = wid * 16 + q;
  bf16x8 bw2[16];
#pragma unroll
  for (int kf2 = 0; kf2 < 16; ++kf2) {
    bf16x8 f;
#pragma unroll
    for (int j = 0; j < 8; ++j) f[j] = (__bf16)Wd2[(kf2 * 32 + g * 8 + j) * 128 + dimf];
    bw2[kf2] = f;
  }
  f32x4 bd2v;
#pragma unroll
  for (int i = 0; i < 4; ++i) bd2v[i] = bd2[wid * 16 + g * 4 + i];

  const int srow = tid >> 4, sk8 = (tid & 15) * 8;
  const int stg_byte = ((srow * 256 + sk8 * 2) ^ ((srow & 7) << 4));
  char* hb = (char*)hbuf;

  float local = 0.f;

  {
    const float* p = z + (size_t)tile0 * 4096 + tid * 8;
    f32x4 r0 = *(const f32x4*)p, r1 = *(const f32x4*)(p + 4);
    bf16x8 v;
#pragma unroll
    for (int j = 0; j < 4; ++j) { v[j] = (__bf16)r0[j]; v[4 + j] = (__bf16)r1[j]; }
    *(bf16x8*)((char*)zbuf[0] + stg_byte) = v;
  }
  f32x4 rA0, rA1, rB0, rB1;
  { const float* p = z + (size_t)(tile0 + 1) * 4096 + tid * 8; rA0 = *(const f32x4*)p; rA1 = *(const f32x4*)(p + 4); }
  { const float* p = z + (size_t)(tile0 + 2) * 4096 + tid * 8; rB0 = *(const f32x4*)p; rB1 = *(const f32x4*)(p + 4); }
  barrier_lds_only();

#define DBODY(T, ZC, RR0, RR1)                                                     \
  do {                                                                             \
    f32x4 acc1[2][4] = {};                                                         \
    char* zc = (char*)zbuf[ZC];                                                    \
    _Pragma("unroll") for (int kf = 0; kf < 4; ++kf) {                             \
      _Pragma("unroll") for (int rf = 0; rf < 2; ++rf) {                           \
        const int row = rf * 16 + q;                                               \
        bf16x8 a = *(const bf16x8*)(zc + ((row * 256 + kf * 64 + g * 16) ^ ((row & 7) << 4))); \
        _Pragma("unroll") for (int cf = 0; cf < 4; ++cf)                           \
          acc1[rf][cf] = __builtin_amdgcn_mfma_f32_16x16x32_bf16(bw1[cf][kf], a, acc1[rf][cf], 0, 0, 0); \
      }                                                                            \
    }                                                                              \
    {                                                                              \
      bf16x8 v;                                                                    \
      _Pragma("unroll") for (int j = 0; j < 4; ++j) { v[j] = (__bf16)RR0[j]; v[4 + j] = (__bf16)RR1[j]; } \
      *(bf16x8*)((char*)zbuf[(ZC) ^ 1] + stg_byte) = v;                            \
    }                                                                              \
    {                                                                              \
      int tl = (T) + 3; if (tl > 3) tl = 3;                                        \
      const float* p = z + (size_t)(tile0 + tl) * 4096 + tid * 8;                  \
      RR0 = *(const f32x4*)p; RR1 = *(const f32x4*)(p + 4);                        \
    }                                                                              \
    _Pragma("unroll") for (int rf = 0; rf < 2; ++rf) {                             \
      const int row = rf * 16 + q;                                                 \
      _Pragma("unroll") for (int cf = 0; cf < 4; ++cf) {                           \
        bf16x4 hv;                                                                 \
        _Pragma("unroll") for (int i = 0; i < 4; ++i)                              \
          hv[i] = (__bf16)fmaxf(acc1[rf][cf][i] + bd1v[cf][i], 0.f);               \
        const int byt = ((row * 1024 + (cb + cf * 16 + g * 4) * 2) ^ ((row & 7) << 4)); \
        *(bf16x4*)(hb + byt) = hv;                                                 \
      }                                                                            \
    }                                                                              \
    barrier_lds_only();                                                            \
    f32x4 acc2[2] = {};                                                            \
    _Pragma("unroll") for (int kf2 = 0; kf2 < 16; ++kf2) {                         \
      _Pragma("unroll") for (int rf2 = 0; rf2 < 2; ++rf2) {                        \
        const int row = rf2 * 16 + q;                                              \
        bf16x8 a = *(const bf16x8*)(hb + ((row * 1024 + kf2 * 64 + g * 16) ^ ((row & 7) << 4))); \
        acc2[rf2] = __builtin_amdgcn_mfma_f32_16x16x32_bf16(bw2[kf2], a, acc2[rf2], 0, 0, 0); \
      }                                                                            \
    }                                                                              \
    const int e = (tile0 + (T)) >> 1;                                              \
    _Pragma("unroll") for (int rf2 = 0; rf2 < 2; ++rf2) {                          \
      float partial = 0.f;                                                         \
      _Pragma("unroll") for (int i = 0; i < 4; ++i) {                              \
        const float xv = mp[e * 128 + wid * 16 + g * 4 + i];                       \
        const float d = xv - (acc2[rf2][i] + bd2v[i]);                             \
        partial += d * d;                                                          \
      }                                                                            \
      partial += __shfl_xor(partial, 16);                                          \
      partial += __shfl_xor(partial, 32);                                          \
      if (lid < 16) s_part[rf2 * 16 + lid][wid] = partial;                         \
    }                                                                              \
    barrier_lds_only();                                                            \
    if (tid < 32) {                                                                \
      float t2 = 0.f;                                                              \
      _Pragma("unroll") for (int w = 0; w < 8; ++w) t2 += s_part[tid][w];          \
      local += (-0.5f * t2 - 0.5f * 128.f * LOG_2PI) * (1.f / 64.f);               \
    }                                                                              \
  } while (0)

#pragma unroll 1
  for (int t = 0; t < 4; t += 2) {
    DBODY(t, 0, rA0, rA1);
    DBODY(t + 1, 1, rB0, rB1);
  }
#undef DBODY

  if (wid == 0) {
#pragma unroll
    for (int m = 16; m >= 1; m >>= 1) local += __shfl_xor(local, m);
    if (lid == 0) atomicAdd(recon_acc, local);
  }
}

// ---------------- finalize --------------------------------------------------
__global__ void finalize_kernel(const float* __restrict__ accs, float* __restrict__ out) {
  // accs: [0]=integral, [1]=log_intensity_sum, [2]=recon, [3]=sum(z_traj^2)
  const float kl = 0.01f * (accs[3] / 67108864.f);  // 8192*64*128
  const float elbo = accs[1] - accs[0] + accs[2] - kl;
  out[0] = -elbo;
}

extern "C" void kernel_launch(void* const* d_in, const int* in_sizes, int n_in,
                              void* d_out, int out_size, void* d_ws, size_t ws_size,
                              hipStream_t stream) {
  const float* event_marks = (const float*)d_in[0];
  const float* z_events = (const float*)d_in[1];
  const float* z_traj = (const float*)d_in[2];
  const float* times = (const float*)d_in[3];
  const float* Wp = (const float*)d_in[4];
  const float* bp = (const float*)d_in[5];
  const float* W1 = (const float*)d_in[6];
  const float* b1 = (const float*)d_in[7];
  const float* W2 = (const float*)d_in[8];
  const float* b2 = (const float*)d_in[9];
  const float* base_i = (const float*)d_in[10];
  const float* Wd1 = (const float*)d_in[11];
  const float* bd1 = (const float*)d_in[12];
  const float* Wd2 = (const float*)d_in[13];
  const float* bd2 = (const float*)d_in[14];

  float* mp = (float*)d_ws;                              // 1024*128 f32
  float* accs = (float*)((char*)d_ws + 1024 * 128 * 4);  // accumulators

  prep_kernel<<<1025, 128, 0, stream>>>(event_marks, Wp, bp, mp, accs);
  intensity8_kernel<<<256, 768, 0, stream>>>(z_traj, z_events, W1, b1, W2, b2,
                                             base_i, times, accs);
  decoder2_kernel<<<512, 512, 0, stream>>>(z_events, Wd1, bd1, Wd2, bd2, mp,
                                           &accs[2]);
  finalize_kernel<<<1, 1, 0, stream>>>(accs, (float*)d_out);
}